// Round 14
// baseline (186.590 us; speedup 1.0000x reference)
//
#include <hip/hip_runtime.h>
#include <hip/hip_bf16.h>
#include <math.h>

#define BATCH 8
#define NPTS 4096
#define CH 128
#define CTG 4                         // column strips per batch (1024 cols each)
#define ROWS 128                      // rows per block (mi=2)
#define CHUNK 32                      // columns per chunk
#define NCHUNK (NPTS / (CTG * CHUNK)) // 32 chunks per block

// exp(s/TEMP) = 2^(s * 10 * log2(e)). sqrt(10/ln2) is folded into the
// normalize scale so the GEMM accumulator is already the exp2 argument.
#define SQRT_TEMP_LOG2E 3.79828256f   // sqrt(14.4269504089)

typedef __attribute__((ext_vector_type(4))) float    f32x4;
typedef __attribute__((ext_vector_type(4))) int      i32x4;
typedef __attribute__((ext_vector_type(8))) short    bf16x8;
typedef __attribute__((ext_vector_type(4))) _Float16 f16x4;

__device__ __forceinline__ float fast_exp2(float x) {
    return __builtin_amdgcn_exp2f(x);
}

// 16x16x16 f16 MFMA. HW-verified convention (R11/R12 refcheck):
//   mfma16(X, Y, C): OUT(lane15 = Y.lane15, elem quad*4+r = X.lane15)
//                  = sum_k X[X.lane15][k] * Y[Y.lane15][k],  k = quad*4+j.
__device__ __forceinline__ f32x4 mfma16(f16x4 a, f16x4 b, f32x4 c) {
#if __has_builtin(__builtin_amdgcn_mfma_f32_16x16x16f16)
    return __builtin_amdgcn_mfma_f32_16x16x16f16(a, b, c, 0, 0, 0);
#else
    f32x4 d = c;
    asm volatile("v_mfma_f32_16x16x16_f16 %0, %1, %2, %0"
                 : "+v"(d) : "v"(a), "v"(b));
    return d;
#endif
}

// ---------------------------------------------------------------------------
// Kernel 1: coalesced two-pass L2-normalize (R9, verified).
// ---------------------------------------------------------------------------
__global__ __launch_bounds__(256) void normalize_kernel(
    const float* __restrict__ f, __hip_bfloat16* __restrict__ vn,
    float* __restrict__ pos, float* __restrict__ neg, float* __restrict__ out)
{
    const int blk = blockIdx.x;            // 512 blocks
    const int b = blk >> 6;                // 64 blocks per batch
    const int n0 = (blk & 63) * 64;        // 64 points per block
    const int nl = threadIdx.x & 63;       // point lane
    const int cg = threadIdx.x >> 6;       // channel quarter (32 ch)
    const float* base = f + (size_t)b * CH * NPTS + (size_t)(cg * 32) * NPTS
                          + n0 + nl;

    __shared__ float red[4][64];
    __shared__ float scl[64];
    __shared__ short ostage[64 * CH];      // 16 KB staging tile

    float ss = 0.0f;
    #pragma unroll
    for (int c = 0; c < 32; c++) {
        float v = base[(size_t)c * NPTS];
        ss += v * v;
    }
    red[cg][nl] = ss;
    __syncthreads();
    if (cg == 0) {
        float s = red[0][nl] + red[1][nl] + red[2][nl] + red[3][nl];
        scl[nl] = SQRT_TEMP_LOG2E / fmaxf(sqrtf(s), 1e-12f);
    }
    __syncthreads();
    const float scale = scl[nl];

    #pragma unroll
    for (int k = 0; k < 4; k++) {
        union { __hip_bfloat16 h[8]; uint4 u; } pk;
        #pragma unroll
        for (int j = 0; j < 8; j++) {
            float v = base[(size_t)(k * 8 + j) * NPTS] * scale;
            pk.h[j] = __float2bfloat16(v);
        }
        const int ch8 = cg * 4 + k;
        const int phys = (nl << 4) | (ch8 ^ (nl & 15));
        *(uint4*)&ostage[phys * 8] = pk.u;
    }
    __syncthreads();

    __hip_bfloat16* ob = vn + ((size_t)b * NPTS + n0) * CH;
    const int t = threadIdx.x;
    #pragma unroll
    for (int it = 0; it < 4; it++) {
        const int L = it * 256 + t;
        const int pt = L >> 4, c8 = L & 15;
        const int phys = (pt << 4) | (c8 ^ (pt & 15));
        *(uint4*)(ob + (size_t)L * 8) = *(const uint4*)&ostage[phys * 8];
    }

    if (cg == 0) pos[b * NPTS + n0 + nl] = 0.0f;
    else if (cg == 1) neg[b * NPTS + n0 + nl] = 0.0f;
    if (blk == 0 && t == 0) out[0] = 0.0f;
}

// ---------------------------------------------------------------------------
// Kernel 2: BARRIER-FREE dataflow GEMM (R13 resubmit — R13's bench was an
// infra failure, "container failed twice", no kernel signal; source audited
// for hang/fault risks: uniform control flow, in-bounds labL staging, imm
// offsets < 8191B — resubmitting byte-identical to preserve the A/B).
//
// R5..R12 consolidated: every structural variant kept a barrier-lockstep
// skeleton and every one plateaued at 46-62us with both pipes <50% —
// including R12, where HALVING the pipe work left the wall unchanged
// (serialization-bound, not pipe-bound). This version removes the skeleton:
// NO LDS staging of B, NO s_barrier / asm vmcnt in the loop. Each wave loads
// its own B-fragments directly from global:
//   addr(lane; c, ni, ks) = vb + (colbase + lane15)*CH + quad*8   [per-lane]
//                           + c*8192B                             [per chunk]
//                           + ni*4096B + ks*64B                   [imm offset]
// so a chunk is 8 global_load_dwordx4 off one address register (all imm
// offsets <= 4288 < 8191). The block's 4 waves read identical 8KB -> L1
// broadcast; vn (8MB) is L2/L3-resident so HBM FETCH stays ~flat. With no
// barriers the compiler pipelines chunk c+1 loads under chunk c MFMA+EPI
// (#pragma unroll 2) and waves drift freely (m114 cross-wave MFMA||VALU).
//
// Math identical to the verified R10 path: swapped-operand 16x16x32 MFMA
//   acc[mi][ni] elem (lane,r) = S[row0+w*32+mi*16+lane15]
//                                [colbase+c*32+ni*16+quad*4+r],
// class-GEMM epilogue (labels in [0,16)) accumulating qout[mi] on the MFMA
// pipe, ddiag diagonal correction, quad-fold + 2 atomics per row.
//
// launch_bounds(256,4): 128-reg unified cap (AGPRs count — R7 lesson).
// Est ~105 base regs; compiler limits prefetch depth to fit. Tripwires:
// WRITE_SIZE (spill), absmax, SQ_LDS_BANK_CONFLICT (~0: only labL reads).
// ---------------------------------------------------------------------------
__global__ __launch_bounds__(256, 4) void tile_kernel(
    const __hip_bfloat16* __restrict__ vn, const int* __restrict__ labels,
    float* __restrict__ pos, float* __restrict__ neg)
{
    __shared__ int labL[NPTS / CTG];       // 1024 strip labels (4 KB)

    const int ctg = blockIdx.x, rt = blockIdx.y, b = blockIdx.z;
    const int tid = threadIdx.x;
    const int w = tid >> 6, lane = tid & 63;
    const int lane15 = lane & 15, quad = lane >> 4;

    const int row0 = rt * ROWS;
    const int colbase = ctg * (NPTS / CTG);
    const __hip_bfloat16* vb = vn + (size_t)b * NPTS * CH;
    const int* labb = labels + b * NPTS;

    // Strip labels -> LDS (one i32x4 per thread), single barrier in kernel.
    ((i32x4*)labL)[tid] = ((const i32x4*)(labb + colbase))[tid];

    bf16x8 afrag[2][4];
    int lr[2];
    #pragma unroll
    for (int mi = 0; mi < 2; mi++) {
        const int row_l = w * 32 + mi * 16 + lane15;
        const __hip_bfloat16* Arow = vb + (size_t)(row0 + row_l) * CH;
        #pragma unroll
        for (int ks = 0; ks < 4; ks++)
            afrag[mi][ks] = *(const bf16x8*)(Arow + (ks * 4 + quad) * 8);
        lr[mi] = labb[row0 + row_l];
    }
    __syncthreads();                       // labL visible; only barrier

    // Per-lane B base: row (colbase + lane15), k-offset quad*8.
    const __hip_bfloat16* vbl = vb + (size_t)(colbase + lane15) * CH + quad * 8;

    f32x4 qout[2] = {{0.0f, 0.0f, 0.0f, 0.0f}, {0.0f, 0.0f, 0.0f, 0.0f}};
    float ddiag[2] = {0.0f, 0.0f};
    const f32x4 zf = {0.0f, 0.0f, 0.0f, 0.0f};

    #pragma unroll 2
    for (int c = 0; c < NCHUNK; c++) {
        // ---- load this chunk's B-fragments (8 x dwordx4, imm offsets).
        const __hip_bfloat16* Bc = vbl + (size_t)c * (CHUNK * CH);
        bf16x8 bf[2][4];
        #pragma unroll
        for (int ni = 0; ni < 2; ni++)
            #pragma unroll
            for (int ks = 0; ks < 4; ks++)
                bf[ni][ks] = *(const bf16x8*)(Bc + ni * 16 * CH + ks * 32);

        // ---- 16 MFMAs, zero-init folded into ks=0.
        f32x4 acc[2][2];
        __builtin_amdgcn_s_setprio(1);
        #pragma unroll
        for (int ni = 0; ni < 2; ni++) {
            acc[0][ni] = __builtin_amdgcn_mfma_f32_16x16x32_bf16(
                bf[ni][0], afrag[0][0], zf, 0, 0, 0);
            acc[1][ni] = __builtin_amdgcn_mfma_f32_16x16x32_bf16(
                bf[ni][0], afrag[1][0], zf, 0, 0, 0);
        }
        #pragma unroll
        for (int ks = 1; ks < 4; ks++)
            #pragma unroll
            for (int ni = 0; ni < 2; ni++) {
                acc[0][ni] = __builtin_amdgcn_mfma_f32_16x16x32_bf16(
                    bf[ni][ks], afrag[0][ks], acc[0][ni], 0, 0, 0);
                acc[1][ni] = __builtin_amdgcn_mfma_f32_16x16x32_bf16(
                    bf[ni][ks], afrag[1][ks], acc[1][ni], 0, 0, 0);
            }
        __builtin_amdgcn_s_setprio(0);

        // ---- epilogue: exp2 + class-GEMM (verified R10 math).
        #pragma unroll
        for (int ni = 0; ni < 2; ni++) {
            const i32x4 lc = *(const i32x4*)&labL[c * CHUNK + ni * 16 + quad * 4];
            f16x4 oh;
            #pragma unroll
            for (int j = 0; j < 4; j++)
                oh[j] = (lc[j] == lane15) ? (_Float16)1.0f : (_Float16)0.0f;
            const int colblk = colbase + c * CHUNK + ni * 16;
            #pragma unroll
            for (int mi = 0; mi < 2; mi++) {
                f16x4 eh;
                #pragma unroll
                for (int r = 0; r < 4; r++)
                    eh[r] = (_Float16)fast_exp2(acc[mi][ni][r]);
                if (colblk == row0 + w * 32 + mi * 16) {   // wave-uniform
                    #pragma unroll
                    for (int r = 0; r < 4; r++)
                        if (lane15 == quad * 4 + r)
                            ddiag[mi] += (float)eh[r];
                }
                qout[mi] = mfma16(oh, eh, qout[mi]);
            }
        }
    }

    // ---- strip done. qout[mi] elem (lane,r) = q[class=quad*4+r, row=lane15].
    #pragma unroll
    for (int mi = 0; mi < 2; mi++) {
        float p = -ddiag[mi], tt = -ddiag[mi];
        #pragma unroll
        for (int r = 0; r < 4; r++) {
            float v = qout[mi][r];
            tt += v;
            p  += (quad * 4 + r == lr[mi]) ? v : 0.0f;
        }
        p  += __shfl_xor(p, 16);   p  += __shfl_xor(p, 32);
        tt += __shfl_xor(tt, 16);  tt += __shfl_xor(tt, 32);
        if (lane < 16) {
            const int row_l = w * 32 + mi * 16 + lane15;
            atomicAdd(&pos[b * NPTS + row0 + row_l], p);
            atomicAdd(&neg[b * NPTS + row0 + row_l], tt - p);
        }
    }
}

// ---------------------------------------------------------------------------
// Kernel 3: mean of log((p+n)/p) over 32768 rows. 32 blocks x 256 threads;
// out zeroed by normalize_kernel, stream order makes the atomic safe.
// ---------------------------------------------------------------------------
__global__ __launch_bounds__(256) void finalize_kernel(
    const float* __restrict__ pos, const float* __restrict__ neg,
    float* __restrict__ out)
{
    int base = blockIdx.x * 1024 + threadIdx.x;
    float acc = 0.0f;
    #pragma unroll
    for (int k = 0; k < 4; k++) {
        int i = base + k * 256;
        float p = pos[i];
        float t = p + neg[i];
        acc += __logf(t / p);   // == -log(p / (p+n))
    }
    #pragma unroll
    for (int off = 32; off; off >>= 1) acc += __shfl_down(acc, off);
    __shared__ float red[4];
    if ((threadIdx.x & 63) == 0) red[threadIdx.x >> 6] = acc;
    __syncthreads();
    if (threadIdx.x == 0) {
        float v = red[0] + red[1] + red[2] + red[3];
        atomicAdd(out, v * (1.0f / (BATCH * NPTS)));
    }
}

extern "C" void kernel_launch(void* const* d_in, const int* in_sizes, int n_in,
                              void* d_out, int out_size, void* d_ws, size_t ws_size,
                              hipStream_t stream)
{
    const float* features = (const float*)d_in[0];
    const int*   labels   = (const int*)d_in[1];
    float*       out      = (float*)d_out;

    // Workspace: vn bf16 [8][4096][128] = 8 MB, then pos/neg fp32.
    __hip_bfloat16* vn = (__hip_bfloat16*)d_ws;
    float* pos = (float*)((char*)d_ws + (size_t)BATCH * NPTS * CH * sizeof(__hip_bfloat16));
    float* neg = pos + BATCH * NPTS;

    // 512 blocks x 64 points, coalesced two-pass normalize (R9, verified).
    hipLaunchKernelGGL(normalize_kernel, dim3(512), dim3(256), 0, stream,
                       features, vn, pos, neg, out);
    // Barrier-free dataflow tiles: 4 ctg x 32 rt x 8 batches = 1024 blocks.
    hipLaunchKernelGGL(tile_kernel, dim3(CTG, NPTS / ROWS, BATCH), dim3(256), 0, stream,
                       vn, labels, pos, neg);
    hipLaunchKernelGGL(finalize_kernel, dim3(32), dim3(256), 0, stream, pos, neg, out);
}